// Round 4
// baseline (5904.458 us; speedup 1.0000x reference)
//
#include <hip/hip_runtime.h>
#include <hip/hip_bf16.h>

typedef __hip_bfloat16 bf16;

__device__ __forceinline__ float b2f(bf16 v){ return __bfloat162float(v); }
__device__ __forceinline__ bf16 f2b(float v){ return __float2bfloat16(v); }

#define CDIM 256
#define NHEADS 8
#define DH 32

// ---------------- NCHW (f32) -> NHWC (bf16) ----------------
__global__ __launch_bounds__(256) void k_nchw2nhwc(const float* __restrict__ x, bf16* __restrict__ o,
                                                   int Hh, int Ww)
{
    long long idx = (long long)blockIdx.x * 256 + threadIdx.x;
    int c = (int)(idx & (CDIM - 1));
    long long t = idx >> 8;
    int w = (int)(t % Ww); t /= Ww;
    int h = (int)(t % Hh); t /= Hh;
    int n = (int)t;
    o[idx] = f2b(x[(((long long)n * CDIM + c) * Hh + h) * Ww + w]);
}

// ---------------- GEMM: C[M,N] = A[M,K] @ B[K,N] (+bias, +relu, +Cadd) ----------------
// A: bf16 (row stride K). B/bias: f32 weights (B row stride ldb). C: bf16 (row stride N).
__global__ __launch_bounds__(256) void k_gemm(const bf16* __restrict__ A, const float* __restrict__ B,
                                              const float* __restrict__ bias, const bf16* __restrict__ Cadd,
                                              bf16* __restrict__ C,
                                              int M, int N, int K, int ldb, int relu)
{
    __shared__ float As[16][66];
    __shared__ float Bs[16][66];
    int tid = threadIdx.x;
    int tx = tid & 15, ty = tid >> 4;
    int row0 = blockIdx.y * 64, col0 = blockIdx.x * 64;
    float acc[4][4] = {};
    for (int k0 = 0; k0 < K; k0 += 16) {
        #pragma unroll
        for (int l = tid; l < 1024; l += 256) {
            int m = l >> 4, kk = l & 15;
            As[kk][m] = b2f(A[(long long)(row0 + m) * K + k0 + kk]);
        }
        #pragma unroll
        for (int l = tid; l < 1024; l += 256) {
            int kk = l >> 6, nn = l & 63;
            Bs[kk][nn] = B[(long long)(k0 + kk) * ldb + col0 + nn];
        }
        __syncthreads();
        #pragma unroll
        for (int kk = 0; kk < 16; ++kk) {
            float a[4], b[4];
            #pragma unroll
            for (int i = 0; i < 4; ++i) a[i] = As[kk][ty * 4 + i];
            #pragma unroll
            for (int j = 0; j < 4; ++j) b[j] = Bs[kk][tx * 4 + j];
            #pragma unroll
            for (int i = 0; i < 4; ++i)
                #pragma unroll
                for (int j = 0; j < 4; ++j)
                    acc[i][j] += a[i] * b[j];
        }
        __syncthreads();
    }
    #pragma unroll
    for (int i = 0; i < 4; ++i) {
        int row = row0 + ty * 4 + i;
        #pragma unroll
        for (int j = 0; j < 4; ++j) {
            int col = col0 + tx * 4 + j;
            float v = acc[i][j];
            if (bias) v += bias[col];
            if (relu) v = fmaxf(v, 0.f);
            if (Cadd) v += b2f(Cadd[(long long)row * N + col]);
            C[(long long)row * N + col] = f2b(v);
        }
    }
}

// ---------------- windowed self-attention (one block = one 8x8 window) ----------------
// O == Q in-place is safe: head h's output channels are written only after head h's Q
// is staged in LDS; later heads read disjoint channels; blocks own disjoint tokens.
__global__ __launch_bounds__(256) void k_attn_self(const bf16* __restrict__ Q, const bf16* __restrict__ K,
                                                   const bf16* __restrict__ V, bf16* __restrict__ O,
                                                   int Hh, int Ww)
{
    __shared__ float sq[64][33], sk[64][33], sv[64][33];
    __shared__ float S[64][65];
    __shared__ int toki[64];
    int tid = threadIdx.x;
    int nw = Ww >> 3, nh = Hh >> 3;
    int win = blockIdx.x;
    int n = win / (nh * nw);
    int rem = win - n * (nh * nw);
    int wi = rem / nw, wj = rem - (rem / nw) * nw;
    if (tid < 64) {
        int r = tid >> 3, c2 = tid & 7;
        toki[tid] = (n * Hh + wi * 8 + r) * Ww + wj * 8 + c2;
    }
    __syncthreads();
    const float scale = 0.17677669529663687f; // 1/sqrt(32)
    for (int h = 0; h < NHEADS; ++h) {
        for (int l = tid; l < 64 * 32; l += 256) {
            int t = l >> 5, d = l & 31;
            long long base = (long long)toki[t] * CDIM + h * DH + d;
            sq[t][d] = b2f(Q[base]);
            sk[t][d] = b2f(K[base]);
            sv[t][d] = b2f(V[base]);
        }
        __syncthreads();
        for (int l = tid; l < 64 * 64; l += 256) {
            int qi = l >> 6, ki = l & 63;
            float s = 0.f;
            #pragma unroll
            for (int d = 0; d < 32; ++d) s += sq[qi][d] * sk[ki][d];
            S[qi][ki] = s * scale;
        }
        __syncthreads();
        if (tid < 64) {
            float m = -1e30f;
            for (int i = 0; i < 64; ++i) m = fmaxf(m, S[tid][i]);
            float sum = 0.f;
            for (int i = 0; i < 64; ++i) { float e = __expf(S[tid][i] - m); S[tid][i] = e; sum += e; }
            float inv = 1.f / sum;
            for (int i = 0; i < 64; ++i) S[tid][i] *= inv;
        }
        __syncthreads();
        for (int l = tid; l < 64 * 32; l += 256) {
            int t = l >> 5, d = l & 31;
            float o = 0.f;
            #pragma unroll
            for (int k2 = 0; k2 < 64; ++k2) o += S[t][k2] * sv[k2][d];
            O[(long long)toki[t] * CDIM + h * DH + d] = f2b(o);
        }
        __syncthreads();
    }
}

// ---------------- cross-attention: Q map (8,128,128,C), KV map (8,32,32,C) ----------------
__global__ __launch_bounds__(256) void k_attn_cross(const bf16* __restrict__ Q, const bf16* __restrict__ Kc,
                                                    const bf16* __restrict__ Vc, bf16* __restrict__ O)
{
    __shared__ float sq[64][33], sk[64][33], sv[64][33];
    __shared__ float S[64][65];
    __shared__ int qtok[64], ktok[64];
    int tid = threadIdx.x;
    int win = blockIdx.x;
    int n = win >> 8, wi = (win >> 4) & 15, wj = win & 15;
    if (tid < 64) {
        int r = tid >> 3, c2 = tid & 7;
        qtok[tid] = (n * 128 + wi * 8 + r) * 128 + wj * 8 + c2;
        ktok[tid] = (n * 32 + ((wi * 2 + r) & 31)) * 32 + ((wj * 2 + c2) & 31); // circular pad
    }
    __syncthreads();
    const float scale = 0.17677669529663687f;
    for (int h = 0; h < NHEADS; ++h) {
        for (int l = tid; l < 64 * 32; l += 256) {
            int t = l >> 5, d = l & 31;
            sq[t][d] = b2f(Q[(long long)qtok[t] * CDIM + h * DH + d]);
            long long kb = (long long)ktok[t] * CDIM + h * DH + d;
            sk[t][d] = b2f(Kc[kb]);
            sv[t][d] = b2f(Vc[kb]);
        }
        __syncthreads();
        for (int l = tid; l < 64 * 64; l += 256) {
            int qi = l >> 6, ki = l & 63;
            float s = 0.f;
            #pragma unroll
            for (int d = 0; d < 32; ++d) s += sq[qi][d] * sk[ki][d];
            S[qi][ki] = s * scale;
        }
        __syncthreads();
        if (tid < 64) {
            float m = -1e30f;
            for (int i = 0; i < 64; ++i) m = fmaxf(m, S[tid][i]);
            float sum = 0.f;
            for (int i = 0; i < 64; ++i) { float e = __expf(S[tid][i] - m); S[tid][i] = e; sum += e; }
            float inv = 1.f / sum;
            for (int i = 0; i < 64; ++i) S[tid][i] *= inv;
        }
        __syncthreads();
        for (int l = tid; l < 64 * 32; l += 256) {
            int t = l >> 5, d = l & 31;
            float o = 0.f;
            #pragma unroll
            for (int k2 = 0; k2 < 64; ++k2) o += S[t][k2] * sv[k2][d];
            O[(long long)qtok[t] * CDIM + h * DH + d] = f2b(o);
        }
        __syncthreads();
    }
}

// ---------------- LayerNorm(A + B) * g + beta -> bf16 NHWC ----------------
__global__ __launch_bounds__(256) void k_ln(const bf16* __restrict__ A, const bf16* __restrict__ Bb,
                                            const float* __restrict__ g, const float* __restrict__ be,
                                            bf16* __restrict__ O)
{
    __shared__ float red[8];
    __shared__ float mv[2];
    int tok = blockIdx.x, c = threadIdx.x;
    float v = b2f(A[(long long)tok * CDIM + c]) + b2f(Bb[(long long)tok * CDIM + c]);
    float s = v, s2 = v * v;
    #pragma unroll
    for (int off = 32; off > 0; off >>= 1) { s += __shfl_down(s, off); s2 += __shfl_down(s2, off); }
    int lane = threadIdx.x & 63, wv = threadIdx.x >> 6;
    if (lane == 0) { red[wv] = s; red[4 + wv] = s2; }
    __syncthreads();
    if (threadIdx.x == 0) {
        float ts = red[0] + red[1] + red[2] + red[3];
        float ts2 = red[4] + red[5] + red[6] + red[7];
        float mu = ts * (1.f / 256.f);
        mv[0] = mu; mv[1] = ts2 * (1.f / 256.f) - mu * mu;
    }
    __syncthreads();
    float y = (v - mv[0]) * rsqrtf(mv[1] + 1e-5f) * g[c] + be[c];
    O[(long long)tok * CDIM + c] = f2b(y);
}

// ---------------- final LayerNorm(A + B) -> FLOAT32 output, NHWC->NCHW ----------------
__global__ __launch_bounds__(256) void k_ln_out(const bf16* __restrict__ A, const bf16* __restrict__ Bb,
                                                const float* __restrict__ g, const float* __restrict__ be,
                                                float* __restrict__ O, int HW)
{
    __shared__ float red[8];
    __shared__ float mv[2];
    int tok = blockIdx.x, c = threadIdx.x;
    float v = b2f(A[(long long)tok * CDIM + c]) + b2f(Bb[(long long)tok * CDIM + c]);
    float s = v, s2 = v * v;
    #pragma unroll
    for (int off = 32; off > 0; off >>= 1) { s += __shfl_down(s, off); s2 += __shfl_down(s2, off); }
    int lane = threadIdx.x & 63, wv = threadIdx.x >> 6;
    if (lane == 0) { red[wv] = s; red[4 + wv] = s2; }
    __syncthreads();
    if (threadIdx.x == 0) {
        float ts = red[0] + red[1] + red[2] + red[3];
        float ts2 = red[4] + red[5] + red[6] + red[7];
        float mu = ts * (1.f / 256.f);
        mv[0] = mu; mv[1] = ts2 * (1.f / 256.f) - mu * mu;
    }
    __syncthreads();
    float y = (v - mv[0]) * rsqrtf(mv[1] + 1e-5f) * g[c] + be[c];
    int n = tok / HW, hw = tok - n * HW;
    O[((long long)n * CDIM + c) * HW + hw] = y;   // fp32 NCHW output
}

// ---------------- 4x4 average pool ----------------
__global__ __launch_bounds__(256) void k_pool(const bf16* __restrict__ A, bf16* __restrict__ P,
                                              int Hin, int Win)
{
    int tok = blockIdx.x, c = threadIdx.x;
    int Wo = Win >> 2, Ho = Hin >> 2;
    int n = tok / (Ho * Wo);
    int rem = tok - n * (Ho * Wo);
    int i = rem / Wo, j = rem - (rem / Wo) * Wo;
    float s = 0.f;
    #pragma unroll
    for (int di = 0; di < 4; ++di)
        #pragma unroll
        for (int dj = 0; dj < 4; ++dj)
            s += b2f(A[(((long long)n * Hin + i * 4 + di) * Win + j * 4 + dj) * CDIM + c]);
    P[(long long)tok * CDIM + c] = f2b(s * 0.0625f);
}

extern "C" void kernel_launch(void* const* d_in, const int* in_sizes, int n_in,
                              void* d_out, int out_size, void* d_ws, size_t ws_size,
                              hipStream_t stream)
{
    const float* x     = (const float*)d_in[0];
    const float* sa_wq = (const float*)d_in[1];
    const float* sa_wk = (const float*)d_in[2];
    const float* sa_wv = (const float*)d_in[3];
    const float* sa_wf = (const float*)d_in[4];
    const float* sa_bf = (const float*)d_in[5];
    const float* ca_wq = (const float*)d_in[6];
    const float* ca_wk = (const float*)d_in[7];
    const float* ca_wv = (const float*)d_in[8];
    const float* ca_wf = (const float*)d_in[9];
    const float* ca_bf = (const float*)d_in[10];
    const float* lns_g = (const float*)d_in[11];
    const float* lns_b = (const float*)d_in[12];
    const float* lnc_g = (const float*)d_in[13];
    const float* lnc_b = (const float*)d_in[14];
    const float* w1    = (const float*)d_in[15];
    const float* b1    = (const float*)d_in[16];
    const float* w2    = (const float*)d_in[17];
    const float* b2    = (const float*)d_in[18];
    const float* lno_g = (const float*)d_in[19];
    const float* lno_b = (const float*)d_in[20];
    float* out = (float*)d_out;   // fp32 output, per reference dtype

    const int TOK0 = 8 * 128 * 128;   // 131072
    const int TOK1 = 8 * 32 * 32;     // 8192
    const size_t S0  = (size_t)TOK0 * CDIM * sizeof(bf16); // 64 MiB
    const size_t SML = (size_t)TOK1 * CDIM * sizeof(bf16); // 4 MiB
    char* ws = (char*)d_ws;
    // Peak workspace: exactly 4 * 64 MiB = 256 MiB.
    bf16* W0 = (bf16*)(ws);
    bf16* W1 = (bf16*)(ws + S0);
    bf16* W2 = (bf16*)(ws + 2 * S0);
    bf16* W3 = (bf16*)(ws + 3 * S0);
    // small (TOK1) buffers packed inside W0 once W0 is dead:
    bf16* P1 = (bf16*)(ws + 0 * SML);
    bf16* Q1 = (bf16*)(ws + 1 * SML);
    bf16* K1 = (bf16*)(ws + 2 * SML);
    bf16* V1 = (bf16*)(ws + 3 * SML);
    bf16* J1 = (bf16*)(ws + 4 * SML);
    bf16* A1 = (bf16*)(ws + 5 * SML);
    bf16* Kc = (bf16*)(ws + 6 * SML);
    bf16* Vc = (bf16*)(ws + 7 * SML);

    dim3 blk(256);
    dim3 g0(4, TOK0 / 64);
    dim3 g1(4, TOK1 / 64);
    dim3 gH(8, TOK0 / 64);

    // ---- level 0 self-attention ----
    k_nchw2nhwc<<<TOK0, blk, 0, stream>>>(x, W0, 128, 128);
    k_gemm<<<g0, blk, 0, stream>>>(W0, sa_wq, nullptr, nullptr, W1, TOK0, 256, 256, 256, 0);
    k_gemm<<<g0, blk, 0, stream>>>(W0, sa_wk, nullptr, nullptr, W2, TOK0, 256, 256, 256, 0);
    k_gemm<<<g0, blk, 0, stream>>>(W0, sa_wv, nullptr, nullptr, W3, TOK0, 256, 256, 256, 0);
    k_attn_self<<<TOK0 / 64, blk, 0, stream>>>(W1, W2, W3, W1, 128, 128);
    k_gemm<<<g0, blk, 0, stream>>>(W1, sa_wf, sa_bf, nullptr, W2, TOK0, 256, 256, 256, 0);
    k_ln<<<TOK0, blk, 0, stream>>>(W0, W2, lns_g, lns_b, W3);                         // W3 = A0

    // ---- level 1 self-attention ----
    k_pool<<<TOK1, blk, 0, stream>>>(W3, P1, 128, 128);
    k_gemm<<<g1, blk, 0, stream>>>(P1, sa_wq, nullptr, nullptr, Q1, TOK1, 256, 256, 256, 0);
    k_gemm<<<g1, blk, 0, stream>>>(P1, sa_wk, nullptr, nullptr, K1, TOK1, 256, 256, 256, 0);
    k_gemm<<<g1, blk, 0, stream>>>(P1, sa_wv, nullptr, nullptr, V1, TOK1, 256, 256, 256, 0);
    k_attn_self<<<TOK1 / 64, blk, 0, stream>>>(Q1, K1, V1, Q1, 32, 32);
    k_gemm<<<g1, blk, 0, stream>>>(Q1, sa_wf, sa_bf, nullptr, J1, TOK1, 256, 256, 256, 0);
    k_ln<<<TOK1, blk, 0, stream>>>(P1, J1, lns_g, lns_b, A1);                         // A1

    // ---- cross-attention ----
    k_gemm<<<g0, blk, 0, stream>>>(W3, ca_wq, nullptr, nullptr, W1, TOK0, 256, 256, 256, 0);
    k_gemm<<<g1, blk, 0, stream>>>(A1, ca_wk, nullptr, nullptr, Kc, TOK1, 256, 256, 256, 0);
    k_gemm<<<g1, blk, 0, stream>>>(A1, ca_wv, nullptr, nullptr, Vc, TOK1, 256, 256, 256, 0);
    k_attn_cross<<<TOK0 / 64, blk, 0, stream>>>(W1, Kc, Vc, W1);
    k_gemm<<<g0, blk, 0, stream>>>(W1, ca_wf, ca_bf, nullptr, W2, TOK0, 256, 256, 256, 0);
    k_ln<<<TOK0, blk, 0, stream>>>(W3, W2, lnc_g, lnc_b, W1);                         // W1 = q

    // ---- FFN (hidden split 2x512, exact) + final LN -> fp32 NCHW ----
    k_gemm<<<gH, blk, 0, stream>>>(W1, w1, b1, nullptr, W2, TOK0, 512, 256, 1024, 1);
    k_gemm<<<g0, blk, 0, stream>>>(W2, w2, b2, nullptr, W0, TOK0, 256, 512, 256, 0);
    k_gemm<<<gH, blk, 0, stream>>>(W1, w1 + 512, b1 + 512, nullptr, W2, TOK0, 512, 256, 1024, 1);
    k_gemm<<<g0, blk, 0, stream>>>(W2, w2 + 512 * 256, nullptr, W0, W0, TOK0, 256, 512, 256, 0);
    k_ln_out<<<TOK0, blk, 0, stream>>>(W1, W0, lno_g, lno_b, out, 128 * 128);
}